// Round 2
// baseline (901.748 us; speedup 1.0000x reference)
//
#include <hip/hip_runtime.h>
#include <math.h>

#define MD 128
#define NA 2048
#define AS 512
#define NS 32768
#define NBE 512
#define W1 1792
#define W2 2304
#define PI 3.14159265358979323846
#define KTH ((float)(PI / 98304.0))

__device__ __forceinline__ float lrelu(float v) { return v > 0.f ? v : 0.2f * v; }

// ---------------------------------------------------------------------------
// Kernel 1: per-(b,e) MLP stacks + gumbel argmax + filter/params build.
// G[be][512] = (-1)^tau * atoms[idx][tau]*inv_norm * amp * (-1)^(m0+1)*sin(pi*frac)/N
// params[be][3] float4: {uc, lo, hi, M0}, {M1..M4}, {M5, M6, 0, 0}
//   uc = m0 + frac + 255.5 ;  M_k = sum_tau G[tau] * (-(tau-255.5)*pi/N)^k
// ---------------------------------------------------------------------------
__global__ __launch_bounds__(128) void prep_kernel(
    const float* __restrict__ x, const float* __restrict__ times,
    const float* __restrict__ gu, const float* __restrict__ atoms,
    const float* __restrict__ tw0, const float* __restrict__ tb0,
    const float* __restrict__ tw1, const float* __restrict__ tb1,
    const float* __restrict__ tw2, const float* __restrict__ tb2,
    const float* __restrict__ sw0, const float* __restrict__ sb0,
    const float* __restrict__ sw1, const float* __restrict__ sb1,
    const float* __restrict__ sw2, const float* __restrict__ sb2,
    const float* __restrict__ aw0, const float* __restrict__ ab0,
    const float* __restrict__ aw1, const float* __restrict__ ab1,
    const float* __restrict__ aw2, const float* __restrict__ ab2,
    float* __restrict__ G, int* __restrict__ m0s, float* __restrict__ fracs,
    float4* __restrict__ params)
{
  const int be = blockIdx.x;
  const int tid = threadIdx.x;
  __shared__ float xs[MD];
  __shared__ double dh[MD], dh2[MD], dred[128];
  __shared__ float h1[MD], h2[MD], red[128];
  __shared__ float m_red[128][8];
  __shared__ int redi[128];
  __shared__ float sc_time, sc_amp, sc_coef, sc_inv, sc_fr;
  __shared__ int sc_idx, sc_m0;

  xs[tid] = x[be * MD + tid];
  __syncthreads();

  // ---- time stack (fp64: dNc = 32767*dtime, precision-critical) ----
  {
    double s = (double)tb0[tid];
    for (int k = 0; k < MD; ++k) s += (double)xs[k] * (double)tw0[k * MD + tid];
    dh[tid] = s > 0.0 ? s : 0.2 * s;
    __syncthreads();
    double s2 = (double)tb1[tid];
    for (int k = 0; k < MD; ++k) s2 += dh[k] * (double)tw1[k * MD + tid];
    dh2[tid] = s2 > 0.0 ? s2 : 0.2 * s2;
    __syncthreads();
    dred[tid] = dh2[tid] * (double)tw2[tid];
    __syncthreads();
    for (int off = 64; off > 0; off >>= 1) {
      if (tid < off) dred[tid] += dred[tid + off];
      __syncthreads();
    }
    if (tid == 0) {
      double tval = dred[0] + (double)tb2[0];
      double sg = 1.0 / (1.0 + exp(-tval));
      float tf = (float)sg;
      sc_time = tf * 1.0f + times[be];
    }
    __syncthreads();
  }

  // ---- amp stack (fp32) ----
  {
    float s = ab0[tid];
    for (int k = 0; k < MD; ++k) s += xs[k] * aw0[k * MD + tid];
    h1[tid] = lrelu(s);
    __syncthreads();
    float s2 = ab1[tid];
    for (int k = 0; k < MD; ++k) s2 += h1[k] * aw1[k * MD + tid];
    h2[tid] = lrelu(s2);
    __syncthreads();
    red[tid] = h2[tid] * aw2[tid];
    __syncthreads();
    for (int off = 64; off > 0; off >>= 1) {
      if (tid < off) red[tid] += red[tid + off];
      __syncthreads();
    }
    if (tid == 0) {
      float av = red[0] + ab2[0];
      sc_amp = av * av;
    }
    __syncthreads();
  }

  // ---- selection stack (fp32) + gumbel argmax ----
  {
    float s = sb0[tid];
    for (int k = 0; k < MD; ++k) s += xs[k] * sw0[k * MD + tid];
    h1[tid] = lrelu(s);
    __syncthreads();
    float s2 = sb1[tid];
    for (int k = 0; k < MD; ++k) s2 += h1[k] * sw1[k * MD + tid];
    h2[tid] = lrelu(s2);
    __syncthreads();
    float best = -3.4e38f;
    int bi = 0;
    for (int o = tid; o < NA; o += 128) {
      float sv = sb2[o];
      for (int k = 0; k < MD; ++k) sv += h2[k] * sw2[k * NA + o];
      float u = gu[be * NA + o];
      float gv = -logf(-logf(u + 1e-10f) + 1e-10f);
      float v = sv + gv;
      if (v > best) { best = v; bi = o; }
    }
    red[tid] = best; redi[tid] = bi;
    __syncthreads();
    for (int off = 64; off > 0; off >>= 1) {
      if (tid < off) {
        float ov = red[tid + off]; int oi = redi[tid + off];
        if (ov > red[tid] || (ov == red[tid] && oi < redi[tid])) { red[tid] = ov; redi[tid] = oi; }
      }
      __syncthreads();
    }
    if (tid == 0) sc_idx = redi[0];
    __syncthreads();
  }

  // ---- atom norm + shift params ----
  const int idx = sc_idx;
  {
    float ss = 0.f;
    for (int i = tid; i < AS; i += 128) { float v = atoms[idx * AS + i]; ss += v * v; }
    red[tid] = ss;
    __syncthreads();
    for (int off = 64; off > 0; off >>= 1) {
      if (tid < off) red[tid] += red[tid + off];
      __syncthreads();
    }
    if (tid == 0) {
      sc_inv = 1.f / (sqrtf(red[0]) + 1e-8f);
      double Nc = (double)sc_time * (1610612736.0 / 49153.0);
      double rr = rint(Nc);
      int m0 = (int)rr;
      float fr = (float)(Nc - rr);
      if (fabsf(fr) < 1e-9f) fr = (fr < 0.f) ? -1e-9f : 1e-9f;
      m0s[be] = m0; sc_m0 = m0;
      fracs[be] = fr; sc_fr = fr;
      sc_coef = sc_amp * ((m0 & 1) ? 1.0f : -1.0f) *
                sinf((float)PI * fr) * (1.0f / 98304.0f);
    }
    __syncthreads();
  }

  // ---- G write + moments ----
  const float cf = sc_coef * sc_inv;
  float mk[7] = {0.f, 0.f, 0.f, 0.f, 0.f, 0.f, 0.f};
  for (int t = tid; t < AS; t += 128) {
    float av = atoms[idx * AS + t] * cf;
    float gv = (t & 1) ? -av : av;
    G[be * AS + t] = gv;
    float q = (255.5f - (float)t) * KTH;   // -(tau-255.5)*pi/N
    float pw = gv;
    mk[0] += pw;
#pragma unroll
    for (int k = 1; k < 7; ++k) { pw *= q; mk[k] += pw; }
  }
#pragma unroll
  for (int k = 0; k < 7; ++k) m_red[tid][k] = mk[k];
  __syncthreads();
  for (int off = 64; off > 0; off >>= 1) {
    if (tid < off) {
#pragma unroll
      for (int k = 0; k < 7; ++k) m_red[tid][k] += m_red[tid + off][k];
    }
    __syncthreads();
  }
  if (tid == 0) {
    float uc = (float)((double)sc_m0 + (double)sc_fr + 255.5);
    params[be * 3 + 0] = make_float4(uc, (float)(sc_m0 - W1), (float)(sc_m0 + W2), m_red[0][0]);
    params[be * 3 + 1] = make_float4(m_red[0][1], m_red[0][2], m_red[0][3], m_red[0][4]);
    params[be * 3 + 2] = make_float4(m_red[0][5], m_red[0][6], 0.f, 0.f);
  }
}

// ---------------------------------------------------------------------------
// Kernel 2 (far field): per (b,t), sum over all 64 e of the P=6 Taylor series
// of cot around the tap center; masked off inside each e's near window.
// Writes every output element (plain store, no memset needed).
// ---------------------------------------------------------------------------
__global__ __launch_bounds__(256) void far_kernel(
    const float4* __restrict__ params, float* __restrict__ out)
{
  const int b = blockIdx.y;
  const int t = blockIdx.x * 256 + threadIdx.x;
  __shared__ float4 Pl[192];
  if (threadIdx.x < 192) Pl[threadIdx.x] = params[b * 192 + threadIdx.x];
  __syncthreads();

  const float tf = (float)t;
  float acc = 0.f;
#pragma unroll 2
  for (int e = 0; e < 64; ++e) {
    const float4 A = Pl[e * 3 + 0];
    const float4 B = Pl[e * 3 + 1];
    const float4 C = Pl[e * 3 + 2];
    float u  = tf - A.x;
    float th = u * KTH;
    float sn = __sinf(th);
    float cs = __cosf(th);
    float c  = cs * __builtin_amdgcn_rcpf(sn);
    // Taylor coeffs of cot at th: a0=c, a1=-(1+c^2), recurrence (k+1)a_{k+1}=-sum a_j a_{k-j}
    float u2  = __builtin_fmaf(c, c, 1.f);     // -a1
    float c2  = c + c;
    float u22 = u2 + u2;
    float a2  = c * u2;
    float a3  = (-1.f / 3.f) * __builtin_fmaf(c2, a2, u2 * u2);
    float a4  = 0.5f * __builtin_fmaf(-c, a3, u2 * a2);
    float s5  = __builtin_fmaf(c2, a4, a2 * a2);
    s5        = __builtin_fmaf(-u22, a3, s5);
    float a5  = -0.2f * s5;
    float s6  = __builtin_fmaf(c, a5, a2 * a3);
    s6        = __builtin_fmaf(-u2, a4, s6);
    float a6  = (-1.f / 3.f) * s6;
    float y = c * A.w;
    y = __builtin_fmaf(-u2, B.x, y);
    y = __builtin_fmaf(a2, B.y, y);
    y = __builtin_fmaf(a3, B.z, y);
    y = __builtin_fmaf(a4, B.w, y);
    y = __builtin_fmaf(a5, C.x, y);
    y = __builtin_fmaf(a6, C.y, y);
    bool farq = (tf < A.y) || (tf >= A.z);
    acc += farq ? y : 0.f;
  }
  out[b * NS + t] = (t & 1) ? -acc : acc;
}

// ---------------------------------------------------------------------------
// Kernel 3 (near field): direct 512-tap conv over the 4096-sample window
// around t = m0, one (b,e) per block, 2 tile-halves. atomicAdd on top of far.
// LDS swizzle g ^= (g>>3)&7: 16 lanes cover each bank-class twice (2-way free).
// ---------------------------------------------------------------------------
__global__ __launch_bounds__(256) void near_kernel(
    const float* __restrict__ G, const int* __restrict__ m0s,
    const float* __restrict__ fracs, float* __restrict__ out)
{
  const int be = blockIdx.y;
  const int m0 = m0s[be];
  const int t0 = m0 - W1 + blockIdx.x * 2048;
  if (t0 >= NS) return;                       // uniform: whole block exits
  const float fr = fracs[be];
  const int b = be >> 6;
  const int tid = threadIdx.x;

  __shared__ float4 Tl4[640];                 // logical v = t0-511 .. t0+2047
  __shared__ float4 Gl4[128];
  float* Tl = (float*)Tl4;
  float* Gl = (float*)Gl4;

  for (int i = tid; i < AS; i += 256) Gl[i] = G[be * AS + i];
  for (int i = tid; i < 2559; i += 256) {
    int v = t0 - 511 + i;
    float w = (float)(v - m0) - fr;
    float th = w * KTH;
    float sn, cs;
    sincosf(th, &sn, &cs);                    // libm: relative-accurate at pole
    float val = cs / sn;
    int g = i >> 2;
    int gs = g ^ ((g >> 3) & 7);
    Tl[(gs << 2) | (i & 3)] = val;
  }
  __syncthreads();

  float acc[8];
#pragma unroll
  for (int r = 0; r < 8; ++r) acc[r] = 0.f;

  float Wf[16];
  {
    int g0 = 2 * tid;     float4 q0 = Tl4[g0 ^ ((g0 >> 3) & 7)];
    int g1 = 2 * tid + 1; float4 q1 = Tl4[g1 ^ ((g1 >> 3) & 7)];
    Wf[0] = q0.x; Wf[1] = q0.y; Wf[2] = q0.z; Wf[3] = q0.w;
    Wf[4] = q1.x; Wf[5] = q1.y; Wf[6] = q1.z; Wf[7] = q1.w;
  }
#pragma unroll
  for (int k = 0; k < 64; ++k) {
    const int gA = 2 * tid + 2 * k + 2;
    const int gB = gA + 1;
    float4 qa = Tl4[gA ^ ((gA >> 3) & 7)];
    float4 qb = Tl4[gB ^ ((gB >> 3) & 7)];
    Wf[8]  = qa.x; Wf[9]  = qa.y; Wf[10] = qa.z; Wf[11] = qa.w;
    Wf[12] = qb.x; Wf[13] = qb.y; Wf[14] = qb.z; Wf[15] = qb.w;
    const int tc = 504 - 8 * k;
    const float4 gq0 = Gl4[tc >> 2];
    const float4 gq1 = Gl4[(tc >> 2) + 1];
    const float gvals[8] = {gq0.x, gq0.y, gq0.z, gq0.w,
                            gq1.x, gq1.y, gq1.z, gq1.w};
#pragma unroll
    for (int d = 0; d < 8; ++d) {
      const float gv = gvals[d];
#pragma unroll
      for (int r = 0; r < 8; ++r)
        acc[r] = fmaf(gv, Wf[7 + r - d], acc[r]);
    }
#pragma unroll
    for (int m = 0; m < 8; ++m) Wf[m] = Wf[m + 8];
  }

  const int tb = t0 + tid * 8;
#pragma unroll
  for (int r = 0; r < 8; ++r) {
    int t = tb + r;
    if (t >= 0 && t < NS) {
      float v = (t & 1) ? -acc[r] : acc[r];
      atomicAdd(&out[b * NS + t], v);
    }
  }
}

// ---------------------------------------------------------------------------
extern "C" void kernel_launch(void* const* d_in, const int* in_sizes, int n_in,
                              void* d_out, int out_size, void* d_ws, size_t ws_size,
                              hipStream_t stream) {
  const float* x     = (const float*)d_in[0];
  const float* times = (const float*)d_in[1];
  const float* gu    = (const float*)d_in[2];
  const float* atoms = (const float*)d_in[3];
  const float* tw0 = (const float*)d_in[4];  const float* tb0 = (const float*)d_in[5];
  const float* tw1 = (const float*)d_in[6];  const float* tb1 = (const float*)d_in[7];
  const float* tw2 = (const float*)d_in[8];  const float* tb2 = (const float*)d_in[9];
  const float* sw0 = (const float*)d_in[10]; const float* sb0 = (const float*)d_in[11];
  const float* sw1 = (const float*)d_in[12]; const float* sb1 = (const float*)d_in[13];
  const float* sw2 = (const float*)d_in[14]; const float* sb2 = (const float*)d_in[15];
  const float* aw0 = (const float*)d_in[16]; const float* ab0 = (const float*)d_in[17];
  const float* aw1 = (const float*)d_in[18]; const float* ab1 = (const float*)d_in[19];
  const float* aw2 = (const float*)d_in[20]; const float* ab2 = (const float*)d_in[21];

  // ws: G (1MB) | m0s (2KB) | fracs (2KB) | params (24KB)
  char* wsb = (char*)d_ws;
  float*  G      = (float*)wsb;
  int*    m0s    = (int*)(wsb + (size_t)NBE * AS * sizeof(float));
  float*  fracs  = (float*)(wsb + (size_t)NBE * AS * sizeof(float) + 2048);
  float4* params = (float4*)(wsb + (size_t)NBE * AS * sizeof(float) + 4096);

  prep_kernel<<<NBE, 128, 0, stream>>>(x, times, gu, atoms,
                                       tw0, tb0, tw1, tb1, tw2, tb2,
                                       sw0, sb0, sw1, sb1, sw2, sb2,
                                       aw0, ab0, aw1, ab1, aw2, ab2,
                                       G, m0s, fracs, params);

  far_kernel<<<dim3(NS / 256, 8), 256, 0, stream>>>(params, (float*)d_out);

  near_kernel<<<dim3(2, NBE), 256, 0, stream>>>(G, m0s, fracs, (float*)d_out);
}

// Round 3
// 202.028 us; speedup vs baseline: 4.4635x; 4.4635x over previous
//
#include <hip/hip_runtime.h>
#include <math.h>

#define MD 128
#define NA 2048
#define AS 512
#define NS 32768
#define NBE 512
#define W1 1792
#define W2 2304
#define PI 3.14159265358979323846
#define KTH ((float)(PI / 98304.0))

__device__ __forceinline__ float lrelu(float v) { return v > 0.f ? v : 0.2f * v; }

// ---------------------------------------------------------------------------
// Kernel 1: per-(b,e) MLP stacks + gumbel argmax + filter/params build.
// G[be][512] = (-1)^tau * atoms[idx][tau]*inv_norm * amp * (-1)^(m0+1)*sin(pi*frac)/N
// params[be][3] float4: {uc, lo, hi, M0}, {M1..M4}, {M5, M6, 0, 0}
//   uc = m0 + frac + 255.5 ;  M_k = sum_tau G[tau] * (-(tau-255.5)*pi/N)^k
// ---------------------------------------------------------------------------
__global__ __launch_bounds__(128) void prep_kernel(
    const float* __restrict__ x, const float* __restrict__ times,
    const float* __restrict__ gu, const float* __restrict__ atoms,
    const float* __restrict__ tw0, const float* __restrict__ tb0,
    const float* __restrict__ tw1, const float* __restrict__ tb1,
    const float* __restrict__ tw2, const float* __restrict__ tb2,
    const float* __restrict__ sw0, const float* __restrict__ sb0,
    const float* __restrict__ sw1, const float* __restrict__ sb1,
    const float* __restrict__ sw2, const float* __restrict__ sb2,
    const float* __restrict__ aw0, const float* __restrict__ ab0,
    const float* __restrict__ aw1, const float* __restrict__ ab1,
    const float* __restrict__ aw2, const float* __restrict__ ab2,
    float* __restrict__ G, int* __restrict__ m0s, float* __restrict__ fracs,
    float4* __restrict__ params)
{
  const int be = blockIdx.x;
  const int tid = threadIdx.x;
  __shared__ float xs[MD];
  __shared__ double dh[MD], dh2[MD], dred[128];
  __shared__ float h1[MD], h2[MD], red[128];
  __shared__ float m_red[128][8];
  __shared__ int redi[128];
  __shared__ float sc_time, sc_amp, sc_coef, sc_inv, sc_fr;
  __shared__ int sc_idx, sc_m0;

  xs[tid] = x[be * MD + tid];
  __syncthreads();

  // ---- time stack (fp64: dNc = 32767*dtime, precision-critical) ----
  {
    double s = (double)tb0[tid];
    for (int k = 0; k < MD; ++k) s += (double)xs[k] * (double)tw0[k * MD + tid];
    dh[tid] = s > 0.0 ? s : 0.2 * s;
    __syncthreads();
    double s2 = (double)tb1[tid];
    for (int k = 0; k < MD; ++k) s2 += dh[k] * (double)tw1[k * MD + tid];
    dh2[tid] = s2 > 0.0 ? s2 : 0.2 * s2;
    __syncthreads();
    dred[tid] = dh2[tid] * (double)tw2[tid];
    __syncthreads();
    for (int off = 64; off > 0; off >>= 1) {
      if (tid < off) dred[tid] += dred[tid + off];
      __syncthreads();
    }
    if (tid == 0) {
      double tval = dred[0] + (double)tb2[0];
      double sg = 1.0 / (1.0 + exp(-tval));
      float tf = (float)sg;
      sc_time = tf * 1.0f + times[be];
    }
    __syncthreads();
  }

  // ---- amp stack (fp32) ----
  {
    float s = ab0[tid];
    for (int k = 0; k < MD; ++k) s += xs[k] * aw0[k * MD + tid];
    h1[tid] = lrelu(s);
    __syncthreads();
    float s2 = ab1[tid];
    for (int k = 0; k < MD; ++k) s2 += h1[k] * aw1[k * MD + tid];
    h2[tid] = lrelu(s2);
    __syncthreads();
    red[tid] = h2[tid] * aw2[tid];
    __syncthreads();
    for (int off = 64; off > 0; off >>= 1) {
      if (tid < off) red[tid] += red[tid + off];
      __syncthreads();
    }
    if (tid == 0) {
      float av = red[0] + ab2[0];
      sc_amp = av * av;
    }
    __syncthreads();
  }

  // ---- selection stack (fp32) + gumbel argmax ----
  {
    float s = sb0[tid];
    for (int k = 0; k < MD; ++k) s += xs[k] * sw0[k * MD + tid];
    h1[tid] = lrelu(s);
    __syncthreads();
    float s2 = sb1[tid];
    for (int k = 0; k < MD; ++k) s2 += h1[k] * sw1[k * MD + tid];
    h2[tid] = lrelu(s2);
    __syncthreads();
    float best = -3.4e38f;
    int bi = 0;
    for (int o = tid; o < NA; o += 128) {
      float sv = sb2[o];
      for (int k = 0; k < MD; ++k) sv += h2[k] * sw2[k * NA + o];
      float u = gu[be * NA + o];
      float gv = -logf(-logf(u + 1e-10f) + 1e-10f);
      float v = sv + gv;
      if (v > best) { best = v; bi = o; }
    }
    red[tid] = best; redi[tid] = bi;
    __syncthreads();
    for (int off = 64; off > 0; off >>= 1) {
      if (tid < off) {
        float ov = red[tid + off]; int oi = redi[tid + off];
        if (ov > red[tid] || (ov == red[tid] && oi < redi[tid])) { red[tid] = ov; redi[tid] = oi; }
      }
      __syncthreads();
    }
    if (tid == 0) sc_idx = redi[0];
    __syncthreads();
  }

  // ---- atom norm + shift params ----
  const int idx = sc_idx;
  {
    float ss = 0.f;
    for (int i = tid; i < AS; i += 128) { float v = atoms[idx * AS + i]; ss += v * v; }
    red[tid] = ss;
    __syncthreads();
    for (int off = 64; off > 0; off >>= 1) {
      if (tid < off) red[tid] += red[tid + off];
      __syncthreads();
    }
    if (tid == 0) {
      sc_inv = 1.f / (sqrtf(red[0]) + 1e-8f);
      double Nc = (double)sc_time * (1610612736.0 / 49153.0);
      double rr = rint(Nc);
      int m0 = (int)rr;
      float fr = (float)(Nc - rr);
      if (fabsf(fr) < 1e-9f) fr = (fr < 0.f) ? -1e-9f : 1e-9f;
      m0s[be] = m0; sc_m0 = m0;
      fracs[be] = fr; sc_fr = fr;
      sc_coef = sc_amp * ((m0 & 1) ? 1.0f : -1.0f) *
                sinf((float)PI * fr) * (1.0f / 98304.0f);
    }
    __syncthreads();
  }

  // ---- G write + moments ----
  const float cf = sc_coef * sc_inv;
  float mk[7] = {0.f, 0.f, 0.f, 0.f, 0.f, 0.f, 0.f};
  for (int t = tid; t < AS; t += 128) {
    float av = atoms[idx * AS + t] * cf;
    float gv = (t & 1) ? -av : av;
    G[be * AS + t] = gv;
    float q = (255.5f - (float)t) * KTH;   // -(tau-255.5)*pi/N
    float pw = gv;
    mk[0] += pw;
#pragma unroll
    for (int k = 1; k < 7; ++k) { pw *= q; mk[k] += pw; }
  }
#pragma unroll
  for (int k = 0; k < 7; ++k) m_red[tid][k] = mk[k];
  __syncthreads();
  for (int off = 64; off > 0; off >>= 1) {
    if (tid < off) {
#pragma unroll
      for (int k = 0; k < 7; ++k) m_red[tid][k] += m_red[tid + off][k];
    }
    __syncthreads();
  }
  if (tid == 0) {
    float uc = (float)((double)sc_m0 + (double)sc_fr + 255.5);
    params[be * 3 + 0] = make_float4(uc, (float)(sc_m0 - W1), (float)(sc_m0 + W2), m_red[0][0]);
    params[be * 3 + 1] = make_float4(m_red[0][1], m_red[0][2], m_red[0][3], m_red[0][4]);
    params[be * 3 + 2] = make_float4(m_red[0][5], m_red[0][6], 0.f, 0.f);
  }
}

// ---------------------------------------------------------------------------
// Kernel 2 (far field): per (b,t), sum over all 64 e of the P=6 Taylor series
// of cot around the tap center; masked off inside each e's near window.
// Writes every output element (plain store, no memset needed).
// ---------------------------------------------------------------------------
__global__ __launch_bounds__(256) void far_kernel(
    const float4* __restrict__ params, float* __restrict__ out)
{
  const int b = blockIdx.y;
  const int t = blockIdx.x * 256 + threadIdx.x;
  __shared__ float4 Pl[192];
  if (threadIdx.x < 192) Pl[threadIdx.x] = params[b * 192 + threadIdx.x];
  __syncthreads();

  const float tf = (float)t;
  float acc = 0.f;
#pragma unroll 2
  for (int e = 0; e < 64; ++e) {
    const float4 A = Pl[e * 3 + 0];
    const float4 B = Pl[e * 3 + 1];
    const float4 C = Pl[e * 3 + 2];
    float u  = tf - A.x;
    float th = u * KTH;
    float sn = __sinf(th);
    float cs = __cosf(th);
    float c  = cs * __builtin_amdgcn_rcpf(sn);
    // Taylor coeffs of cot at th: a0=c, a1=-(1+c^2), (k+1)a_{k+1}=-sum a_j a_{k-j}
    float u2  = __builtin_fmaf(c, c, 1.f);     // -a1
    float c2  = c + c;
    float u22 = u2 + u2;
    float a2  = c * u2;
    float a3  = (-1.f / 3.f) * __builtin_fmaf(c2, a2, u2 * u2);
    float a4  = 0.5f * __builtin_fmaf(-c, a3, u2 * a2);
    float s5  = __builtin_fmaf(c2, a4, a2 * a2);
    s5        = __builtin_fmaf(-u22, a3, s5);
    float a5  = -0.2f * s5;
    float s6  = __builtin_fmaf(c, a5, a2 * a3);
    s6        = __builtin_fmaf(-u2, a4, s6);
    float a6  = (-1.f / 3.f) * s6;
    float y = c * A.w;
    y = __builtin_fmaf(-u2, B.x, y);
    y = __builtin_fmaf(a2, B.y, y);
    y = __builtin_fmaf(a3, B.z, y);
    y = __builtin_fmaf(a4, B.w, y);
    y = __builtin_fmaf(a5, C.x, y);
    y = __builtin_fmaf(a6, C.y, y);
    bool farq = (tf < A.y) || (tf >= A.z);
    acc += farq ? y : 0.f;
  }
  out[b * NS + t] = (t & 1) ? -acc : acc;
}

// ---------------------------------------------------------------------------
// Kernel 3 (near field): round-1 conv structure (proven VGPR=100 codegen):
// grid (16 tiles, 8 b, 8 eg), inner loop over 8 e's with block-uniform
// overlap skip; per-e conv into tmp[8], masked-accumulated into acc[8]
// (mask complementary to far's), single unconditional atomicAdd epilogue.
// #pragma unroll 8 on k-loop caps live LDS-window regs (anti-spill).
// ---------------------------------------------------------------------------
__global__ __launch_bounds__(256) void near_kernel(
    const float* __restrict__ G, const int* __restrict__ m0s,
    const float* __restrict__ fracs, float* __restrict__ out)
{
  const int tile = blockIdx.x;   // 0..15
  const int b    = blockIdx.y;   // 0..7
  const int eg   = blockIdx.z;   // 0..7
  const int tid  = threadIdx.x;
  const int t0   = tile * 2048;

  __shared__ float4 Tl4[640];    // logical v = t0-511 .. t0+2047
  __shared__ float4 Gl4[128];
  float* Tl = (float*)Tl4;
  float* Gl = (float*)Gl4;

  float acc[8];
#pragma unroll
  for (int r = 0; r < 8; ++r) acc[r] = 0.f;

  for (int ei = 0; ei < 8; ++ei) {
    const int be = b * 64 + eg * 8 + ei;
    const int m0 = m0s[be];
    const int lo = m0 - W1, hi = m0 + W2;
    if (lo >= t0 + 2048 || hi <= t0) continue;   // block-uniform skip

    __syncthreads();  // previous e's reads done before refill
    for (int i = tid; i < AS; i += 256) Gl[i] = G[be * AS + i];
    const float fr = fracs[be];
    for (int i = tid; i < 2559; i += 256) {
      int v = t0 - 511 + i;
      float w = (float)(v - m0) - fr;
      float th = w * KTH;
      float sn, cs;
      sincosf(th, &sn, &cs);                 // libm: relative-accurate at pole
      float val = cs / sn;
      int g = i >> 2;
      int gs = g ^ ((g >> 3) & 7);
      Tl[(gs << 2) | (i & 3)] = val;
    }
    __syncthreads();

    float tmp[8];
#pragma unroll
    for (int r = 0; r < 8; ++r) tmp[r] = 0.f;

    float Wf[16];
    {
      int g0 = 2 * tid;     float4 q0 = Tl4[g0 ^ ((g0 >> 3) & 7)];
      int g1 = 2 * tid + 1; float4 q1 = Tl4[g1 ^ ((g1 >> 3) & 7)];
      Wf[0] = q0.x; Wf[1] = q0.y; Wf[2] = q0.z; Wf[3] = q0.w;
      Wf[4] = q1.x; Wf[5] = q1.y; Wf[6] = q1.z; Wf[7] = q1.w;
    }
#pragma unroll 8
    for (int k = 0; k < 64; ++k) {
      const int gA = 2 * tid + 2 * k + 2;
      const int gB = gA + 1;
      float4 qa = Tl4[gA ^ ((gA >> 3) & 7)];
      float4 qb = Tl4[gB ^ ((gB >> 3) & 7)];
      Wf[8]  = qa.x; Wf[9]  = qa.y; Wf[10] = qa.z; Wf[11] = qa.w;
      Wf[12] = qb.x; Wf[13] = qb.y; Wf[14] = qb.z; Wf[15] = qb.w;
      const int tc = 504 - 8 * k;
      const float4 gq0 = Gl4[tc >> 2];
      const float4 gq1 = Gl4[(tc >> 2) + 1];
      const float gvals[8] = {gq0.x, gq0.y, gq0.z, gq0.w,
                              gq1.x, gq1.y, gq1.z, gq1.w};
#pragma unroll
      for (int d = 0; d < 8; ++d) {
        const float gv = gvals[d];
#pragma unroll
        for (int r = 0; r < 8; ++r)
          tmp[r] = fmaf(gv, Wf[7 + r - d], tmp[r]);
      }
#pragma unroll
      for (int m = 0; m < 8; ++m) Wf[m] = Wf[m + 8];
    }

    const int tb = t0 + tid * 8;
#pragma unroll
    for (int r = 0; r < 8; ++r) {
      int t = tb + r;
      acc[r] += (t >= lo && t < hi) ? tmp[r] : 0.f;   // complement of far mask
    }
  }

  const int tbase = t0 + tid * 8;
#pragma unroll
  for (int r = 0; r < 8; ++r) {
    float v = (r & 1) ? -acc[r] : acc[r];   // (-1)^t; t0, tid*8 even
    atomicAdd(&out[b * NS + tbase + r], v);
  }
}

// ---------------------------------------------------------------------------
extern "C" void kernel_launch(void* const* d_in, const int* in_sizes, int n_in,
                              void* d_out, int out_size, void* d_ws, size_t ws_size,
                              hipStream_t stream) {
  const float* x     = (const float*)d_in[0];
  const float* times = (const float*)d_in[1];
  const float* gu    = (const float*)d_in[2];
  const float* atoms = (const float*)d_in[3];
  const float* tw0 = (const float*)d_in[4];  const float* tb0 = (const float*)d_in[5];
  const float* tw1 = (const float*)d_in[6];  const float* tb1 = (const float*)d_in[7];
  const float* tw2 = (const float*)d_in[8];  const float* tb2 = (const float*)d_in[9];
  const float* sw0 = (const float*)d_in[10]; const float* sb0 = (const float*)d_in[11];
  const float* sw1 = (const float*)d_in[12]; const float* sb1 = (const float*)d_in[13];
  const float* sw2 = (const float*)d_in[14]; const float* sb2 = (const float*)d_in[15];
  const float* aw0 = (const float*)d_in[16]; const float* ab0 = (const float*)d_in[17];
  const float* aw1 = (const float*)d_in[18]; const float* ab1 = (const float*)d_in[19];
  const float* aw2 = (const float*)d_in[20]; const float* ab2 = (const float*)d_in[21];

  // ws: G (1MB) | m0s (2KB) | fracs (2KB) | params (24KB)
  char* wsb = (char*)d_ws;
  float*  G      = (float*)wsb;
  int*    m0s    = (int*)(wsb + (size_t)NBE * AS * sizeof(float));
  float*  fracs  = (float*)(wsb + (size_t)NBE * AS * sizeof(float) + 2048);
  float4* params = (float4*)(wsb + (size_t)NBE * AS * sizeof(float) + 4096);

  prep_kernel<<<NBE, 128, 0, stream>>>(x, times, gu, atoms,
                                       tw0, tb0, tw1, tb1, tw2, tb2,
                                       sw0, sb0, sw1, sb1, sw2, sb2,
                                       aw0, ab0, aw1, ab1, aw2, ab2,
                                       G, m0s, fracs, params);

  far_kernel<<<dim3(NS / 256, 8), 256, 0, stream>>>(params, (float*)d_out);

  near_kernel<<<dim3(16, 8, 8), 256, 0, stream>>>(G, m0s, fracs, (float*)d_out);
}

// Round 4
// 120.488 us; speedup vs baseline: 7.4841x; 1.6767x over previous
//
#include <hip/hip_runtime.h>
#include <math.h>

#define MD 128
#define NA 2048
#define AS 512
#define NS 32768
#define NBE 512
#define W1 1792
#define W2 2304
#define PI 3.14159265358979323846
#define KTH ((float)(PI / 98304.0))

__device__ __forceinline__ float lrelu(float v) { return v > 0.f ? v : 0.2f * v; }

// ---------------------------------------------------------------------------
// Kernel 1: per-(b,e) MLP stacks + gumbel argmax + filter/params build.
// G[be][512] = (-1)^tau * atoms[idx][tau]*inv_norm * amp * (-1)^(m0+1)*sin(pi*frac)/N
// params[be][3] float4: {uc, lo, hi, M0}, {M1..M4}, {M5, M6, 0, 0}
//   uc = m0 + frac + 255.5 ;  M_k = sum_tau G[tau] * (-(tau-255.5)*pi/N)^k
// ---------------------------------------------------------------------------
__global__ __launch_bounds__(128) void prep_kernel(
    const float* __restrict__ x, const float* __restrict__ times,
    const float* __restrict__ gu, const float* __restrict__ atoms,
    const float* __restrict__ tw0, const float* __restrict__ tb0,
    const float* __restrict__ tw1, const float* __restrict__ tb1,
    const float* __restrict__ tw2, const float* __restrict__ tb2,
    const float* __restrict__ sw0, const float* __restrict__ sb0,
    const float* __restrict__ sw1, const float* __restrict__ sb1,
    const float* __restrict__ sw2, const float* __restrict__ sb2,
    const float* __restrict__ aw0, const float* __restrict__ ab0,
    const float* __restrict__ aw1, const float* __restrict__ ab1,
    const float* __restrict__ aw2, const float* __restrict__ ab2,
    float* __restrict__ G, int* __restrict__ m0s, float* __restrict__ fracs,
    float4* __restrict__ params)
{
  const int be = blockIdx.x;
  const int tid = threadIdx.x;
  __shared__ float xs[MD];
  __shared__ double dh[MD], dh2[MD], dred[128];
  __shared__ float h1[MD], h2[MD], red[128];
  __shared__ float m_red[128][8];
  __shared__ int redi[128];
  __shared__ float sc_time, sc_amp, sc_coef, sc_inv, sc_fr;
  __shared__ int sc_idx, sc_m0;

  xs[tid] = x[be * MD + tid];
  __syncthreads();

  // ---- time stack (fp64: dNc = 32767*dtime, precision-critical) ----
  {
    double s = (double)tb0[tid];
    for (int k = 0; k < MD; ++k) s += (double)xs[k] * (double)tw0[k * MD + tid];
    dh[tid] = s > 0.0 ? s : 0.2 * s;
    __syncthreads();
    double s2 = (double)tb1[tid];
    for (int k = 0; k < MD; ++k) s2 += dh[k] * (double)tw1[k * MD + tid];
    dh2[tid] = s2 > 0.0 ? s2 : 0.2 * s2;
    __syncthreads();
    dred[tid] = dh2[tid] * (double)tw2[tid];
    __syncthreads();
    for (int off = 64; off > 0; off >>= 1) {
      if (tid < off) dred[tid] += dred[tid + off];
      __syncthreads();
    }
    if (tid == 0) {
      double tval = dred[0] + (double)tb2[0];
      double sg = 1.0 / (1.0 + exp(-tval));
      float tf = (float)sg;
      sc_time = tf * 1.0f + times[be];
    }
    __syncthreads();
  }

  // ---- amp stack (fp32) ----
  {
    float s = ab0[tid];
    for (int k = 0; k < MD; ++k) s += xs[k] * aw0[k * MD + tid];
    h1[tid] = lrelu(s);
    __syncthreads();
    float s2 = ab1[tid];
    for (int k = 0; k < MD; ++k) s2 += h1[k] * aw1[k * MD + tid];
    h2[tid] = lrelu(s2);
    __syncthreads();
    red[tid] = h2[tid] * aw2[tid];
    __syncthreads();
    for (int off = 64; off > 0; off >>= 1) {
      if (tid < off) red[tid] += red[tid + off];
      __syncthreads();
    }
    if (tid == 0) {
      float av = red[0] + ab2[0];
      sc_amp = av * av;
    }
    __syncthreads();
  }

  // ---- selection stack (fp32) + gumbel argmax ----
  {
    float s = sb0[tid];
    for (int k = 0; k < MD; ++k) s += xs[k] * sw0[k * MD + tid];
    h1[tid] = lrelu(s);
    __syncthreads();
    float s2 = sb1[tid];
    for (int k = 0; k < MD; ++k) s2 += h1[k] * sw1[k * MD + tid];
    h2[tid] = lrelu(s2);
    __syncthreads();
    float best = -3.4e38f;
    int bi = 0;
    for (int o = tid; o < NA; o += 128) {
      float sv = sb2[o];
      for (int k = 0; k < MD; ++k) sv += h2[k] * sw2[k * NA + o];
      float u = gu[be * NA + o];
      float gv = -logf(-logf(u + 1e-10f) + 1e-10f);
      float v = sv + gv;
      if (v > best) { best = v; bi = o; }
    }
    red[tid] = best; redi[tid] = bi;
    __syncthreads();
    for (int off = 64; off > 0; off >>= 1) {
      if (tid < off) {
        float ov = red[tid + off]; int oi = redi[tid + off];
        if (ov > red[tid] || (ov == red[tid] && oi < redi[tid])) { red[tid] = ov; redi[tid] = oi; }
      }
      __syncthreads();
    }
    if (tid == 0) sc_idx = redi[0];
    __syncthreads();
  }

  // ---- atom norm + shift params ----
  const int idx = sc_idx;
  {
    float ss = 0.f;
    for (int i = tid; i < AS; i += 128) { float v = atoms[idx * AS + i]; ss += v * v; }
    red[tid] = ss;
    __syncthreads();
    for (int off = 64; off > 0; off >>= 1) {
      if (tid < off) red[tid] += red[tid + off];
      __syncthreads();
    }
    if (tid == 0) {
      sc_inv = 1.f / (sqrtf(red[0]) + 1e-8f);
      double Nc = (double)sc_time * (1610612736.0 / 49153.0);
      double rr = rint(Nc);
      int m0 = (int)rr;
      float fr = (float)(Nc - rr);
      if (fabsf(fr) < 1e-9f) fr = (fr < 0.f) ? -1e-9f : 1e-9f;
      m0s[be] = m0; sc_m0 = m0;
      fracs[be] = fr; sc_fr = fr;
      sc_coef = sc_amp * ((m0 & 1) ? 1.0f : -1.0f) *
                sinf((float)PI * fr) * (1.0f / 98304.0f);
    }
    __syncthreads();
  }

  // ---- G write + moments ----
  const float cf = sc_coef * sc_inv;
  float mk[7] = {0.f, 0.f, 0.f, 0.f, 0.f, 0.f, 0.f};
  for (int t = tid; t < AS; t += 128) {
    float av = atoms[idx * AS + t] * cf;
    float gv = (t & 1) ? -av : av;
    G[be * AS + t] = gv;
    float q = (255.5f - (float)t) * KTH;   // -(tau-255.5)*pi/N
    float pw = gv;
    mk[0] += pw;
#pragma unroll
    for (int k = 1; k < 7; ++k) { pw *= q; mk[k] += pw; }
  }
#pragma unroll
  for (int k = 0; k < 7; ++k) m_red[tid][k] = mk[k];
  __syncthreads();
  for (int off = 64; off > 0; off >>= 1) {
    if (tid < off) {
#pragma unroll
      for (int k = 0; k < 7; ++k) m_red[tid][k] += m_red[tid + off][k];
    }
    __syncthreads();
  }
  if (tid == 0) {
    float uc = (float)((double)sc_m0 + (double)sc_fr + 255.5);
    params[be * 3 + 0] = make_float4(uc, (float)(sc_m0 - W1), (float)(sc_m0 + W2), m_red[0][0]);
    params[be * 3 + 1] = make_float4(m_red[0][1], m_red[0][2], m_red[0][3], m_red[0][4]);
    params[be * 3 + 2] = make_float4(m_red[0][5], m_red[0][6], 0.f, 0.f);
  }
}

// ---------------------------------------------------------------------------
// Kernel 2 (far field): per (b,t), sum over all 64 e of the P=6 Taylor series
// of cot around the tap center; masked off inside each e's near window.
// Writes every output element (plain store, no memset needed).
// ---------------------------------------------------------------------------
__global__ __launch_bounds__(256) void far_kernel(
    const float4* __restrict__ params, float* __restrict__ out)
{
  const int b = blockIdx.y;
  const int t = blockIdx.x * 256 + threadIdx.x;
  __shared__ float4 Pl[192];
  if (threadIdx.x < 192) Pl[threadIdx.x] = params[b * 192 + threadIdx.x];
  __syncthreads();

  const float tf = (float)t;
  float acc = 0.f;
#pragma unroll 2
  for (int e = 0; e < 64; ++e) {
    const float4 A = Pl[e * 3 + 0];
    const float4 B = Pl[e * 3 + 1];
    const float4 C = Pl[e * 3 + 2];
    float u  = tf - A.x;
    float th = u * KTH;
    float sn = __sinf(th);
    float cs = __cosf(th);
    float c  = cs * __builtin_amdgcn_rcpf(sn);
    // Taylor coeffs of cot at th: a0=c, a1=-(1+c^2), (k+1)a_{k+1}=-sum a_j a_{k-j}
    float u2  = __builtin_fmaf(c, c, 1.f);     // -a1
    float c2  = c + c;
    float u22 = u2 + u2;
    float a2  = c * u2;
    float a3  = (-1.f / 3.f) * __builtin_fmaf(c2, a2, u2 * u2);
    float a4  = 0.5f * __builtin_fmaf(-c, a3, u2 * a2);
    float s5  = __builtin_fmaf(c2, a4, a2 * a2);
    s5        = __builtin_fmaf(-u22, a3, s5);
    float a5  = -0.2f * s5;
    float s6  = __builtin_fmaf(c, a5, a2 * a3);
    s6        = __builtin_fmaf(-u2, a4, s6);
    float a6  = (-1.f / 3.f) * s6;
    float y = c * A.w;
    y = __builtin_fmaf(-u2, B.x, y);
    y = __builtin_fmaf(a2, B.y, y);
    y = __builtin_fmaf(a3, B.z, y);
    y = __builtin_fmaf(a4, B.w, y);
    y = __builtin_fmaf(a5, C.x, y);
    y = __builtin_fmaf(a6, C.y, y);
    bool farq = (tf < A.y) || (tf >= A.z);
    acc += farq ? y : 0.f;
  }
  out[b * NS + t] = (t & 1) ? -acc : acc;
}

// ---------------------------------------------------------------------------
// Kernel 3 (near field): one block per (chunk, be); the near window
// [m0-W1, m0+W2) is exactly 2 chunks of 2048. Every active block does exactly
// one table-build + one conv -> balanced, all blocks co-resident.
// cot via Taylor (|theta| <= 0.074): relative-accurate near the pole, no libm.
// LDS swizzle ^((g>>3)&1) (proven lowest-conflict variant, round 1).
// ---------------------------------------------------------------------------
__global__ __launch_bounds__(256) void near_kernel(
    const float* __restrict__ G, const int* __restrict__ m0s,
    const float* __restrict__ fracs, float* __restrict__ out)
{
  const int chunk = blockIdx.x;   // 0..1
  const int be    = blockIdx.y;   // 0..511
  const int tid   = threadIdx.x;
  const int m0 = m0s[be];
  const int start = m0 - W1 + chunk * 2048;
  if (start >= NS) return;        // block-uniform: window past output range
  const float fr = fracs[be];
  const int b = be >> 6;

  __shared__ float4 Tl4[640];     // logical v = start-511 .. start+2047
  __shared__ float4 Gl4[128];
  float* Tl = (float*)Tl4;
  float* Gl = (float*)Gl4;

  for (int i = tid; i < AS; i += 256) Gl[i] = G[be * AS + i];
  for (int i = tid; i < 2559; i += 256) {
    int v = start - 511 + i;
    float w = (float)(v - m0) - fr;           // never 0 (|fr| >= 1e-9)
    float th = w * KTH;                       // |th| <= 0.074
    float q = th * th;
    float sn = th * __builtin_fmaf(q, __builtin_fmaf(q, (1.f / 120.f), (-1.f / 6.f)), 1.f);
    float cs = __builtin_fmaf(q, __builtin_fmaf(q, (1.f / 24.f), -0.5f), 1.f);
    float val = cs * __builtin_amdgcn_rcpf(sn);
    int g = i >> 2;
    int gs = g ^ ((g >> 3) & 1);
    Tl[(gs << 2) | (i & 3)] = val;
  }
  __syncthreads();

  float acc[8];
#pragma unroll
  for (int r = 0; r < 8; ++r) acc[r] = 0.f;

  float Wf[16];
  {
    int g0 = 2 * tid;     float4 q0 = Tl4[g0 ^ ((g0 >> 3) & 1)];
    int g1 = 2 * tid + 1; float4 q1 = Tl4[g1 ^ ((g1 >> 3) & 1)];
    Wf[0] = q0.x; Wf[1] = q0.y; Wf[2] = q0.z; Wf[3] = q0.w;
    Wf[4] = q1.x; Wf[5] = q1.y; Wf[6] = q1.z; Wf[7] = q1.w;
  }
#pragma unroll 8
  for (int k = 0; k < 64; ++k) {
    const int gA = 2 * tid + 2 * k + 2;
    const int gB = gA + 1;
    float4 qa = Tl4[gA ^ ((gA >> 3) & 1)];
    float4 qb = Tl4[gB ^ ((gB >> 3) & 1)];
    Wf[8]  = qa.x; Wf[9]  = qa.y; Wf[10] = qa.z; Wf[11] = qa.w;
    Wf[12] = qb.x; Wf[13] = qb.y; Wf[14] = qb.z; Wf[15] = qb.w;
    const int tc = 504 - 8 * k;
    const float4 gq0 = Gl4[tc >> 2];
    const float4 gq1 = Gl4[(tc >> 2) + 1];
    const float gvals[8] = {gq0.x, gq0.y, gq0.z, gq0.w,
                            gq1.x, gq1.y, gq1.z, gq1.w};
#pragma unroll
    for (int d = 0; d < 8; ++d) {
      const float gv = gvals[d];
#pragma unroll
      for (int r = 0; r < 8; ++r)
        acc[r] = fmaf(gv, Wf[7 + r - d], acc[r]);
    }
#pragma unroll
    for (int m = 0; m < 8; ++m) Wf[m] = Wf[m + 8];
  }

  const int tb = start + tid * 8;
#pragma unroll
  for (int r = 0; r < 8; ++r) {
    int t = tb + r;
    if (t >= 0 && t < NS) {
      float v = (t & 1) ? -acc[r] : acc[r];   // per-element parity (start unaligned)
      atomicAdd(&out[b * NS + t], v);
    }
  }
}

// ---------------------------------------------------------------------------
extern "C" void kernel_launch(void* const* d_in, const int* in_sizes, int n_in,
                              void* d_out, int out_size, void* d_ws, size_t ws_size,
                              hipStream_t stream) {
  const float* x     = (const float*)d_in[0];
  const float* times = (const float*)d_in[1];
  const float* gu    = (const float*)d_in[2];
  const float* atoms = (const float*)d_in[3];
  const float* tw0 = (const float*)d_in[4];  const float* tb0 = (const float*)d_in[5];
  const float* tw1 = (const float*)d_in[6];  const float* tb1 = (const float*)d_in[7];
  const float* tw2 = (const float*)d_in[8];  const float* tb2 = (const float*)d_in[9];
  const float* sw0 = (const float*)d_in[10]; const float* sb0 = (const float*)d_in[11];
  const float* sw1 = (const float*)d_in[12]; const float* sb1 = (const float*)d_in[13];
  const float* sw2 = (const float*)d_in[14]; const float* sb2 = (const float*)d_in[15];
  const float* aw0 = (const float*)d_in[16]; const float* ab0 = (const float*)d_in[17];
  const float* aw1 = (const float*)d_in[18]; const float* ab1 = (const float*)d_in[19];
  const float* aw2 = (const float*)d_in[20]; const float* ab2 = (const float*)d_in[21];

  // ws: G (1MB) | m0s (2KB) | fracs (2KB) | params (24KB)
  char* wsb = (char*)d_ws;
  float*  G      = (float*)wsb;
  int*    m0s    = (int*)(wsb + (size_t)NBE * AS * sizeof(float));
  float*  fracs  = (float*)(wsb + (size_t)NBE * AS * sizeof(float) + 2048);
  float4* params = (float4*)(wsb + (size_t)NBE * AS * sizeof(float) + 4096);

  prep_kernel<<<NBE, 128, 0, stream>>>(x, times, gu, atoms,
                                       tw0, tb0, tw1, tb1, tw2, tb2,
                                       sw0, sb0, sw1, sb1, sw2, sb2,
                                       aw0, ab0, aw1, ab1, aw2, ab2,
                                       G, m0s, fracs, params);

  far_kernel<<<dim3(NS / 256, 8), 256, 0, stream>>>(params, (float*)d_out);

  near_kernel<<<dim3(2, NBE), 256, 0, stream>>>(G, m0s, fracs, (float*)d_out);
}

// Round 5
// 97.841 us; speedup vs baseline: 9.2165x; 1.2315x over previous
//
#include <hip/hip_runtime.h>
#include <math.h>

#define MD 128
#define NA 2048
#define AS 512
#define NS 32768
#define NBE 512
#define W1 1792
#define W2 2304
#define PI 3.14159265358979323846
#define KTH ((float)(PI / 98304.0))

__device__ __forceinline__ float lrelu(float v) { return v > 0.f ? v : 0.2f * v; }

// ---------------------------------------------------------------------------
// P1: hidden layers for all 3 stacks. Grid (128 row-groups, 3 stacks) x 128.
// Each block: 4 rows of one stack. stack0 = time (fp64, full 3 layers ->
// time[be]); stack1 = amp (fp32, 3 layers -> amp[be]); stack2 = sel hidden
// (fp32, 2 layers -> h2sel[be][128]).
// ---------------------------------------------------------------------------
__global__ __launch_bounds__(128) void hidden_kernel(
    const float* __restrict__ x, const float* __restrict__ times,
    const float* __restrict__ tw0, const float* __restrict__ tb0,
    const float* __restrict__ tw1, const float* __restrict__ tb1,
    const float* __restrict__ tw2, const float* __restrict__ tb2,
    const float* __restrict__ sw0, const float* __restrict__ sb0,
    const float* __restrict__ sw1, const float* __restrict__ sb1,
    const float* __restrict__ aw0, const float* __restrict__ ab0,
    const float* __restrict__ aw1, const float* __restrict__ ab1,
    const float* __restrict__ aw2, const float* __restrict__ ab2,
    float* __restrict__ timev, float* __restrict__ ampv,
    float* __restrict__ h2sel)
{
  const int rg = blockIdx.x;      // 0..127 (4 rows each)
  const int stack = blockIdx.y;   // 0=time 1=amp 2=sel
  const int tid = threadIdx.x;

  __shared__ float xs[4][MD];
  __shared__ double dA[4][MD], dB[4][MD];
  __shared__ float fA[4][MD], fB[4][MD];

#pragma unroll
  for (int j = 0; j < 4; ++j) xs[j][tid] = x[(rg * 4 + j) * MD + tid];
  __syncthreads();

  if (stack == 0) {
    // ---- time stack, fp64 ----
    {
      double b = (double)tb0[tid];
      double s[4] = {b, b, b, b};
#pragma unroll 8
      for (int k = 0; k < MD; ++k) {
        double w = (double)tw0[k * MD + tid];
#pragma unroll
        for (int j = 0; j < 4; ++j) s[j] += (double)xs[j][k] * w;
      }
#pragma unroll
      for (int j = 0; j < 4; ++j) dA[j][tid] = s[j] > 0.0 ? s[j] : 0.2 * s[j];
      __syncthreads();
    }
    {
      double b = (double)tb1[tid];
      double s[4] = {b, b, b, b};
#pragma unroll 8
      for (int k = 0; k < MD; ++k) {
        double w = (double)tw1[k * MD + tid];
#pragma unroll
        for (int j = 0; j < 4; ++j) s[j] += dA[j][k] * w;
      }
#pragma unroll
      for (int j = 0; j < 4; ++j) dB[j][tid] = s[j] > 0.0 ? s[j] : 0.2 * s[j];
      __syncthreads();
    }
    {
      double w2 = (double)tw2[tid];
#pragma unroll
      for (int j = 0; j < 4; ++j) dA[j][tid] = dB[j][tid] * w2;
      __syncthreads();
      for (int off = 64; off > 0; off >>= 1) {
        if (tid < off) {
#pragma unroll
          for (int j = 0; j < 4; ++j) dA[j][tid] += dA[j][tid + off];
        }
        __syncthreads();
      }
      if (tid == 0) {
#pragma unroll
        for (int j = 0; j < 4; ++j) {
          double tval = dA[j][0] + (double)tb2[0];
          double sg = 1.0 / (1.0 + exp(-tval));
          float tf = (float)sg;            // round like the fp32 reference
          timev[rg * 4 + j] = tf * 1.0f + times[rg * 4 + j];
        }
      }
    }
  } else if (stack == 1) {
    // ---- amp stack, fp32 ----
    {
      float b = ab0[tid];
      float s[4] = {b, b, b, b};
#pragma unroll 8
      for (int k = 0; k < MD; ++k) {
        float w = aw0[k * MD + tid];
#pragma unroll
        for (int j = 0; j < 4; ++j) s[j] += xs[j][k] * w;
      }
#pragma unroll
      for (int j = 0; j < 4; ++j) fA[j][tid] = lrelu(s[j]);
      __syncthreads();
    }
    {
      float b = ab1[tid];
      float s[4] = {b, b, b, b};
#pragma unroll 8
      for (int k = 0; k < MD; ++k) {
        float w = aw1[k * MD + tid];
#pragma unroll
        for (int j = 0; j < 4; ++j) s[j] += fA[j][k] * w;
      }
#pragma unroll
      for (int j = 0; j < 4; ++j) fB[j][tid] = lrelu(s[j]);
      __syncthreads();
    }
    {
      float w2 = aw2[tid];
#pragma unroll
      for (int j = 0; j < 4; ++j) fA[j][tid] = fB[j][tid] * w2;
      __syncthreads();
      for (int off = 64; off > 0; off >>= 1) {
        if (tid < off) {
#pragma unroll
          for (int j = 0; j < 4; ++j) fA[j][tid] += fA[j][tid + off];
        }
        __syncthreads();
      }
      if (tid == 0) {
#pragma unroll
        for (int j = 0; j < 4; ++j) {
          float av = fA[j][0] + ab2[0];
          ampv[rg * 4 + j] = av * av;
        }
      }
    }
  } else {
    // ---- selection hidden, fp32 ----
    {
      float b = sb0[tid];
      float s[4] = {b, b, b, b};
#pragma unroll 8
      for (int k = 0; k < MD; ++k) {
        float w = sw0[k * MD + tid];
#pragma unroll
        for (int j = 0; j < 4; ++j) s[j] += xs[j][k] * w;
      }
#pragma unroll
      for (int j = 0; j < 4; ++j) fA[j][tid] = lrelu(s[j]);
      __syncthreads();
    }
    {
      float b = sb1[tid];
      float s[4] = {b, b, b, b};
#pragma unroll 8
      for (int k = 0; k < MD; ++k) {
        float w = sw1[k * MD + tid];
#pragma unroll
        for (int j = 0; j < 4; ++j) s[j] += fA[j][k] * w;
      }
#pragma unroll
      for (int j = 0; j < 4; ++j)
        h2sel[(rg * 4 + j) * MD + tid] = lrelu(s[j]);
    }
  }
}

// ---------------------------------------------------------------------------
// P2: selection logits + gumbel + per-tile argmax partials.
// Grid (16 o-tiles, 128 be-groups) x 128. Each block: 128 o's x 4 be's.
// partials[be][ot] = (best_val, best_idx) via wave shuffle reduce.
// ---------------------------------------------------------------------------
__global__ __launch_bounds__(128) void logits_kernel(
    const float* __restrict__ h2sel, const float* __restrict__ gu,
    const float* __restrict__ sw2, const float* __restrict__ sb2,
    float2* __restrict__ partials)
{
  const int ot = blockIdx.x;     // 0..15
  const int beg = blockIdx.y;    // 0..127
  const int tid = threadIdx.x;
  const int o = ot * 128 + tid;
  const int wave = tid >> 6, lane = tid & 63;

  __shared__ float h2s[4][MD];
  __shared__ float wv[2][4];
  __shared__ int wi[2][4];

#pragma unroll
  for (int j = 0; j < 4; ++j) h2s[j][tid] = h2sel[(beg * 4 + j) * MD + tid];
  __syncthreads();

  float b = sb2[o];
  float acc[4] = {b, b, b, b};
#pragma unroll 16
  for (int k = 0; k < MD; ++k) {
    float w = sw2[k * NA + o];
#pragma unroll
    for (int j = 0; j < 4; ++j) acc[j] = fmaf(h2s[j][k], w, acc[j]);
  }

#pragma unroll
  for (int j = 0; j < 4; ++j) {
    float u = gu[(beg * 4 + j) * NA + o];
    float g = -logf(-logf(u + 1e-10f) + 1e-10f);
    float v = acc[j] + g;
    int idx = o;
    // 64-lane shuffle argmax (strict >, tie -> smaller index)
    for (int off = 32; off > 0; off >>= 1) {
      float ov = __shfl_xor(v, off);
      int oi = __shfl_xor(idx, off);
      if (ov > v || (ov == v && oi < idx)) { v = ov; idx = oi; }
    }
    if (lane == 0) { wv[wave][j] = v; wi[wave][j] = idx; }
  }
  __syncthreads();
  if (tid == 0) {
#pragma unroll
    for (int j = 0; j < 4; ++j) {
      float v0 = wv[0][j], v1 = wv[1][j];
      int i0 = wi[0][j], i1 = wi[1][j];
      bool take1 = (v1 > v0) || (v1 == v0 && i1 < i0);
      float bv = take1 ? v1 : v0;
      int bi = take1 ? i1 : i0;
      partials[(beg * 4 + j) * 16 + ot] = make_float2(bv, __int_as_float(bi));
    }
  }
}

// ---------------------------------------------------------------------------
// P3: final argmax + atom norm + shift params + G/moments/params.
// Grid 512 x 128.
// ---------------------------------------------------------------------------
__global__ __launch_bounds__(128) void finalize_kernel(
    const float2* __restrict__ partials, const float* __restrict__ timev,
    const float* __restrict__ ampv, const float* __restrict__ atoms,
    float* __restrict__ G, int* __restrict__ m0s, float* __restrict__ fracs,
    float4* __restrict__ params)
{
  const int be = blockIdx.x;
  const int tid = threadIdx.x;
  __shared__ float red[128];
  __shared__ float m_red[128][8];
  __shared__ float sc_coef, sc_inv;
  __shared__ int sc_idx;

  // ---- final argmax over 16 partials (first wave) ----
  if (tid < 64) {
    float v = -3.4e38f;
    int idx = 0x7fffffff;
    if (tid < 16) {
      float2 p = partials[be * 16 + tid];
      v = p.x;
      idx = __float_as_int(p.y);
    }
    for (int off = 8; off > 0; off >>= 1) {
      float ov = __shfl_xor(v, off);
      int oi = __shfl_xor(idx, off);
      if (ov > v || (ov == v && oi < idx)) { v = ov; idx = oi; }
    }
    if (tid == 0) sc_idx = idx;
  }
  __syncthreads();
  const int idx = sc_idx;

  // ---- atom norm + shift params ----
  {
    float ss = 0.f;
    for (int i = tid; i < AS; i += 128) { float v = atoms[idx * AS + i]; ss += v * v; }
    red[tid] = ss;
    __syncthreads();
    for (int off = 64; off > 0; off >>= 1) {
      if (tid < off) red[tid] += red[tid + off];
      __syncthreads();
    }
    if (tid == 0) {
      sc_inv = 1.f / (sqrtf(red[0]) + 1e-8f);
      double Nc = (double)timev[be] * (1610612736.0 / 49153.0);
      double rr = rint(Nc);
      int m0 = (int)rr;
      float fr = (float)(Nc - rr);
      if (fabsf(fr) < 1e-9f) fr = (fr < 0.f) ? -1e-9f : 1e-9f;
      m0s[be] = m0;
      fracs[be] = fr;
      sc_coef = ampv[be] * ((m0 & 1) ? 1.0f : -1.0f) *
                sinf((float)PI * fr) * (1.0f / 98304.0f);
      red[64] = (float)m0;   // stash for params write
      red[65] = fr;
    }
    __syncthreads();
  }

  // ---- G write + moments ----
  const float cf = sc_coef * sc_inv;
  float mk[7] = {0.f, 0.f, 0.f, 0.f, 0.f, 0.f, 0.f};
  for (int t = tid; t < AS; t += 128) {
    float av = atoms[idx * AS + t] * cf;
    float gv = (t & 1) ? -av : av;
    G[be * AS + t] = gv;
    float q = (255.5f - (float)t) * KTH;
    float pw = gv;
    mk[0] += pw;
#pragma unroll
    for (int k = 1; k < 7; ++k) { pw *= q; mk[k] += pw; }
  }
#pragma unroll
  for (int k = 0; k < 7; ++k) m_red[tid][k] = mk[k];
  __syncthreads();
  for (int off = 64; off > 0; off >>= 1) {
    if (tid < off) {
#pragma unroll
      for (int k = 0; k < 7; ++k) m_red[tid][k] += m_red[tid + off][k];
    }
    __syncthreads();
  }
  if (tid == 0) {
    int m0 = (int)red[64];
    float fr = red[65];
    float uc = (float)((double)m0 + (double)fr + 255.5);
    params[be * 3 + 0] = make_float4(uc, (float)(m0 - W1), (float)(m0 + W2), m_red[0][0]);
    params[be * 3 + 1] = make_float4(m_red[0][1], m_red[0][2], m_red[0][3], m_red[0][4]);
    params[be * 3 + 2] = make_float4(m_red[0][5], m_red[0][6], 0.f, 0.f);
  }
}

// ---------------------------------------------------------------------------
// Far field: per (b,t), P=6 Taylor of cot around each e's tap center.
// ---------------------------------------------------------------------------
__global__ __launch_bounds__(256) void far_kernel(
    const float4* __restrict__ params, float* __restrict__ out)
{
  const int b = blockIdx.y;
  const int t = blockIdx.x * 256 + threadIdx.x;
  __shared__ float4 Pl[192];
  if (threadIdx.x < 192) Pl[threadIdx.x] = params[b * 192 + threadIdx.x];
  __syncthreads();

  const float tf = (float)t;
  float acc = 0.f;
#pragma unroll 2
  for (int e = 0; e < 64; ++e) {
    const float4 A = Pl[e * 3 + 0];
    const float4 B = Pl[e * 3 + 1];
    const float4 C = Pl[e * 3 + 2];
    float u  = tf - A.x;
    float th = u * KTH;
    float sn = __sinf(th);
    float cs = __cosf(th);
    float c  = cs * __builtin_amdgcn_rcpf(sn);
    float u2  = __builtin_fmaf(c, c, 1.f);
    float c2  = c + c;
    float u22 = u2 + u2;
    float a2  = c * u2;
    float a3  = (-1.f / 3.f) * __builtin_fmaf(c2, a2, u2 * u2);
    float a4  = 0.5f * __builtin_fmaf(-c, a3, u2 * a2);
    float s5  = __builtin_fmaf(c2, a4, a2 * a2);
    s5        = __builtin_fmaf(-u22, a3, s5);
    float a5  = -0.2f * s5;
    float s6  = __builtin_fmaf(c, a5, a2 * a3);
    s6        = __builtin_fmaf(-u2, a4, s6);
    float a6  = (-1.f / 3.f) * s6;
    float y = c * A.w;
    y = __builtin_fmaf(-u2, B.x, y);
    y = __builtin_fmaf(a2, B.y, y);
    y = __builtin_fmaf(a3, B.z, y);
    y = __builtin_fmaf(a4, B.w, y);
    y = __builtin_fmaf(a5, C.x, y);
    y = __builtin_fmaf(a6, C.y, y);
    bool farq = (tf < A.y) || (tf >= A.z);
    acc += farq ? y : 0.f;
  }
  out[b * NS + t] = (t & 1) ? -acc : acc;
}

// ---------------------------------------------------------------------------
// Near field: one block per (chunk, be); near window = exactly 2x2048 chunks.
// cot via Taylor (|theta| <= 0.074, relative-accurate). Swizzle ^((g>>3)&1).
// ---------------------------------------------------------------------------
__global__ __launch_bounds__(256) void near_kernel(
    const float* __restrict__ G, const int* __restrict__ m0s,
    const float* __restrict__ fracs, float* __restrict__ out)
{
  const int chunk = blockIdx.x;   // 0..1
  const int be    = blockIdx.y;   // 0..511
  const int tid   = threadIdx.x;
  const int m0 = m0s[be];
  const int start = m0 - W1 + chunk * 2048;
  if (start >= NS) return;
  const float fr = fracs[be];
  const int b = be >> 6;

  __shared__ float4 Tl4[640];
  __shared__ float4 Gl4[128];
  float* Tl = (float*)Tl4;
  float* Gl = (float*)Gl4;

  for (int i = tid; i < AS; i += 256) Gl[i] = G[be * AS + i];
  for (int i = tid; i < 2559; i += 256) {
    int v = start - 511 + i;
    float w = (float)(v - m0) - fr;
    float th = w * KTH;
    float q = th * th;
    float sn = th * __builtin_fmaf(q, __builtin_fmaf(q, (1.f / 120.f), (-1.f / 6.f)), 1.f);
    float cs = __builtin_fmaf(q, __builtin_fmaf(q, (1.f / 24.f), -0.5f), 1.f);
    float val = cs * __builtin_amdgcn_rcpf(sn);
    int g = i >> 2;
    int gs = g ^ ((g >> 3) & 1);
    Tl[(gs << 2) | (i & 3)] = val;
  }
  __syncthreads();

  float acc[8];
#pragma unroll
  for (int r = 0; r < 8; ++r) acc[r] = 0.f;

  float Wf[16];
  {
    int g0 = 2 * tid;     float4 q0 = Tl4[g0 ^ ((g0 >> 3) & 1)];
    int g1 = 2 * tid + 1; float4 q1 = Tl4[g1 ^ ((g1 >> 3) & 1)];
    Wf[0] = q0.x; Wf[1] = q0.y; Wf[2] = q0.z; Wf[3] = q0.w;
    Wf[4] = q1.x; Wf[5] = q1.y; Wf[6] = q1.z; Wf[7] = q1.w;
  }
#pragma unroll 8
  for (int k = 0; k < 64; ++k) {
    const int gA = 2 * tid + 2 * k + 2;
    const int gB = gA + 1;
    float4 qa = Tl4[gA ^ ((gA >> 3) & 1)];
    float4 qb = Tl4[gB ^ ((gB >> 3) & 1)];
    Wf[8]  = qa.x; Wf[9]  = qa.y; Wf[10] = qa.z; Wf[11] = qa.w;
    Wf[12] = qb.x; Wf[13] = qb.y; Wf[14] = qb.z; Wf[15] = qb.w;
    const int tc = 504 - 8 * k;
    const float4 gq0 = Gl4[tc >> 2];
    const float4 gq1 = Gl4[(tc >> 2) + 1];
    const float gvals[8] = {gq0.x, gq0.y, gq0.z, gq0.w,
                            gq1.x, gq1.y, gq1.z, gq1.w};
#pragma unroll
    for (int d = 0; d < 8; ++d) {
      const float gv = gvals[d];
#pragma unroll
      for (int r = 0; r < 8; ++r)
        acc[r] = fmaf(gv, Wf[7 + r - d], acc[r]);
    }
#pragma unroll
    for (int m = 0; m < 8; ++m) Wf[m] = Wf[m + 8];
  }

  const int tb = start + tid * 8;
#pragma unroll
  for (int r = 0; r < 8; ++r) {
    int t = tb + r;
    if (t >= 0 && t < NS) {
      float v = (t & 1) ? -acc[r] : acc[r];
      atomicAdd(&out[b * NS + t], v);
    }
  }
}

// ---------------------------------------------------------------------------
extern "C" void kernel_launch(void* const* d_in, const int* in_sizes, int n_in,
                              void* d_out, int out_size, void* d_ws, size_t ws_size,
                              hipStream_t stream) {
  const float* x     = (const float*)d_in[0];
  const float* times = (const float*)d_in[1];
  const float* gu    = (const float*)d_in[2];
  const float* atoms = (const float*)d_in[3];
  const float* tw0 = (const float*)d_in[4];  const float* tb0 = (const float*)d_in[5];
  const float* tw1 = (const float*)d_in[6];  const float* tb1 = (const float*)d_in[7];
  const float* tw2 = (const float*)d_in[8];  const float* tb2 = (const float*)d_in[9];
  const float* sw0 = (const float*)d_in[10]; const float* sb0 = (const float*)d_in[11];
  const float* sw1 = (const float*)d_in[12]; const float* sb1 = (const float*)d_in[13];
  const float* sw2 = (const float*)d_in[14]; const float* sb2 = (const float*)d_in[15];
  const float* aw0 = (const float*)d_in[16]; const float* ab0 = (const float*)d_in[17];
  const float* aw1 = (const float*)d_in[18]; const float* ab1 = (const float*)d_in[19];
  const float* aw2 = (const float*)d_in[20]; const float* ab2 = (const float*)d_in[21];

  // ws layout (bytes):
  //   G       0        .. 1048576   (512*512 f32)
  //   m0s     1048576  (2KB)
  //   fracs   1050624  (2KB)
  //   params  1052672  (24KB)
  //   timev   1077248  (2KB)
  //   ampv    1079296  (2KB)
  //   h2sel   1081344  (256KB)
  //   partials 1343488 (64KB)
  char* wsb = (char*)d_ws;
  float*  G        = (float*)wsb;
  int*    m0s      = (int*)(wsb + 1048576);
  float*  fracs    = (float*)(wsb + 1050624);
  float4* params   = (float4*)(wsb + 1052672);
  float*  timev    = (float*)(wsb + 1077248);
  float*  ampv     = (float*)(wsb + 1079296);
  float*  h2sel    = (float*)(wsb + 1081344);
  float2* partials = (float2*)(wsb + 1343488);

  hidden_kernel<<<dim3(NBE / 4, 3), 128, 0, stream>>>(
      x, times, tw0, tb0, tw1, tb1, tw2, tb2,
      sw0, sb0, sw1, sb1, aw0, ab0, aw1, ab1, aw2, ab2,
      timev, ampv, h2sel);

  logits_kernel<<<dim3(16, NBE / 4), 128, 0, stream>>>(h2sel, gu, sw2, sb2, partials);

  finalize_kernel<<<NBE, 128, 0, stream>>>(partials, timev, ampv, atoms,
                                           G, m0s, fracs, params);

  far_kernel<<<dim3(NS / 256, 8), 256, 0, stream>>>(params, (float*)d_out);

  near_kernel<<<dim3(2, NBE), 256, 0, stream>>>(G, m0s, fracs, (float*)d_out);
}